// Round 11
// baseline (10269.680 us; speedup 1.0000x reference)
//
#include <hip/hip_runtime.h>

typedef __attribute__((ext_vector_type(8))) short bf16x8;
typedef __attribute__((ext_vector_type(4))) short bf16x4;
typedef __attribute__((ext_vector_type(4))) float f32x4;

#define TFULL 8192
#define RC 128
#define NB 40
#define BATCH 4
#define SKIP_SZ 4096

#define LDS3(p) ((__attribute__((address_space(3))) void*)(p))
#define GLB1(p) ((const __attribute__((address_space(1))) void*)(p))

// ---- single-block kernel LDS (R10 layout, unchanged) ----
#define XPLANE 16384
#define LDS_BYTES (3 * XPLANE)   // 48 KB

// ---- fused-pair kernel LDS regions (bytes) ----
#define STGH 48                  // staged X left halo (= max H+d1)
#define RX 0                     // 112 cols x 256 B = 28672 : X hi; later gated_{i+1}
#define RG 28672                 // 96 cols  x 256 B = 24576 : gated_i; later y_lo
#define RY (28672 + 24576)       // 96 cols  x 256 B = 24576 : y_i hi
#define LDSB (RY + 24576)        // 77824 B -> 2 WG/CU (2x = 152 KB <= 160)

__device__ __forceinline__ unsigned short f2bf(float f) {
    unsigned u = __builtin_bit_cast(unsigned, f);
    u += 0x7FFFu + ((u >> 16) & 1u);          // round-to-nearest-even
    return (unsigned short)(u >> 16);
}
__device__ __forceinline__ float bf2f(unsigned short h) {
    unsigned u = ((unsigned)h) << 16;
    return __builtin_bit_cast(float, u);
}
// tanh(y)*sigmoid(y) via one fast exp (clamped; saturation exact).
__device__ __forceinline__ float gatef(float y) {
    float yc = fminf(fmaxf(y, -30.f), 30.f);
    float e  = __expf(-yc);
    float e2 = e * e;
    return (1.f - e2) * __builtin_amdgcn_rcpf(1.f + e2)
                      * __builtin_amdgcn_rcpf(1.f + e);
}

// ---------------------------------------------------------------------------
// Pre-pass 1: transpose x [B][128ch][8192col] fp32 -> hi/lo bf16 [B][col][ch]
// ---------------------------------------------------------------------------
__global__ __launch_bounds__(256) void xpose_split(
    const float* __restrict__ x,
    unsigned short* __restrict__ Xh, unsigned short* __restrict__ Xl)
{
    __shared__ float t[32][65];
    const int col0 = blockIdx.x * 64;
    const int ch0  = blockIdx.y * 32;
    const int b    = blockIdx.z;
    const int tid  = threadIdx.x;
    const int tx = tid & 63, ty = tid >> 6;
#pragma unroll
    for (int i = 0; i < 8; ++i) {
        int ch = ty + i * 4;
        t[ch][tx] = x[((size_t)(b * RC + ch0 + ch)) * TFULL + col0 + tx];
    }
    __syncthreads();
    for (int idx = tid; idx < 64 * 32; idx += 256) {
        int col = idx >> 5, ch = idx & 31;
        float v = t[ch][col];
        unsigned short h = f2bf(v);
        unsigned short l = f2bf(v - bf2f(h));
        size_t off = ((size_t)(b * TFULL + col0 + col)) * RC + ch0 + ch;
        Xh[off] = h;
        Xl[off] = l;
    }
}

// ---------------------------------------------------------------------------
// Pre-pass 2: pack weights into per-MFMA-A-fragment layout, hi/lo bf16.
// A[m][k]: lane l holds rows m=16*mf+(l&15), k = 32*ks + (l>>4)*8 + j.
// Dilated k = tap*128 + i. Dst flat: ((blk*KS*8 + ks*8 + mf)*64 + lane)*8 + j.
// ---------------------------------------------------------------------------
__global__ __launch_bounds__(256) void wpack(
    const float* __restrict__ Wd, const float* __restrict__ Wr, const float* __restrict__ Ws,
    unsigned short* __restrict__ Wdh, unsigned short* __restrict__ Wdl,
    unsigned short* __restrict__ Wrh, unsigned short* __restrict__ Wrl,
    unsigned short* __restrict__ Wsh, unsigned short* __restrict__ Wsl)
{
    const int Nd = NB * 4096;
    const int Nr = NB * 2048;
    int id = blockIdx.x * 256 + threadIdx.x;
    const float* src;
    unsigned short *dh, *dl;
    int blk, rloc;
    bool dil = false;
    size_t dbase;
    if (id < Nd)               { dil = true; blk = id >> 12; rloc = id & 4095; dh = Wdh; dl = Wdl; src = Wd; dbase = (size_t)id * 8; }
    else if (id < Nd + Nr)     { int t = id - Nd;      blk = t >> 11; rloc = t & 2047; dh = Wrh; dl = Wrl; src = Wr; dbase = (size_t)t * 8; }
    else if (id < Nd + 2 * Nr) { int t = id - Nd - Nr; blk = t >> 11; rloc = t & 2047; dh = Wsh; dl = Wsl; src = Ws; dbase = (size_t)t * 8; }
    else return;
    const int ks = rloc >> 9, mf = (rloc >> 6) & 7, lane = rloc & 63;
    const int m = mf * 16 + (lane & 15);
    const int kb = ks * 32 + ((lane >> 4) << 3);
    bf16x8 hv, lv;
#pragma unroll
    for (int j = 0; j < 8; ++j) {
        int k = kb + j;
        float w;
        if (dil) {
            int tap = k >> 7, i = k & 127;
            w = src[((((size_t)blk * 128 + m) * 128) + i) * 2 + tap];
        } else {
            w = src[(((size_t)blk * 128 + m) * 128) + k];
        }
        unsigned short h = f2bf(w);
        hv[j] = (short)h;
        lv[j] = (short)f2bf(w - bf2f(h));
    }
    *(bf16x8*)(dh + dbase) = hv;
    *(bf16x8*)(dl + dbase) = lv;
}

// ---------------------------------------------------------------------------
// Single-block step (R10, proven): 512 thr, wave = mf slot x 64 cols,
// 2-product weights x bf16 X, gated bf16, stream exact hi/lo.
// ---------------------------------------------------------------------------
__global__ __launch_bounds__(512, 4) void wn_step(
    const unsigned short* __restrict__ curh, const unsigned short* __restrict__ curl,
    unsigned short* __restrict__ nxth, unsigned short* __restrict__ nxtl,
    const unsigned short* __restrict__ Wdh_i, const unsigned short* __restrict__ Wdl_i,
    const unsigned short* __restrict__ Wrh_i, const unsigned short* __restrict__ Wrl_i,
    const unsigned short* __restrict__ Wsh_i, const unsigned short* __restrict__ Wsl_i,
    const float* __restrict__ br, const float* __restrict__ bs,
    float* __restrict__ skip, int d, int col0)
{
    __shared__ char lds[LDS_BYTES];

    const int tid  = threadIdx.x;
    const int lane = tid & 63;
    const int wave = tid >> 6;
    const int l15  = lane & 15, lq = lane >> 4;
    const int u    = blockIdx.x;
    const int b    = u & 3;
    const int tile0 = col0 + (u >> 2) * 64;
    const size_t xbase = (size_t)b * TFULL * RC;

#pragma unroll
    for (int r = 0; r < 4; ++r) {
        const int j   = wave * 4 + r;
        const int tap = j >> 4;
        const int c4  = (j & 15) * 4;
        const int col = c4 + lq;
        const int chs = l15 ^ (col & 7);
        int cg_ = tile0 + col;
        cg_ = cg_ > TFULL - 1 ? TFULL - 1 : cg_;
        if (!tap) cg_ -= d;
        const unsigned short* gsrc = curh + xbase + (size_t)cg_ * RC + chs * 8;
        char* ldst = lds + tap * XPLANE + c4 * 256;
        __builtin_amdgcn_global_load_lds(GLB1(gsrc), LDS3(ldst), 16, 0, 0);
    }
    __syncthreads();

    f32x4 acc[4];
#pragma unroll
    for (int nf = 0; nf < 4; ++nf) acc[nf] = (f32x4){0.f, 0.f, 0.f, 0.f};

#pragma unroll
    for (int ks = 0; ks < 8; ++ks) {
        const int tap = ks >> 2;
        const int kk  = ks & 3;
        const size_t wi = ((size_t)(ks * 8 + wave) * 64 + lane) * 8;
        bf16x8 ah = *(const bf16x8*)(Wdh_i + wi);
        bf16x8 al = *(const bf16x8*)(Wdl_i + wi);
#pragma unroll
        for (int nf = 0; nf < 4; ++nf) {
            const int col = nf * 16 + l15;
            const int byo = (kk * 64 + lq * 16) ^ ((col & 7) << 4);
            bf16x8 bh = *(const bf16x8*)(lds + tap * XPLANE + col * 256 + byo);
            acc[nf] = __builtin_amdgcn_mfma_f32_16x16x32_bf16(ah, bh, acc[nf], 0, 0, 0);
            acc[nf] = __builtin_amdgcn_mfma_f32_16x16x32_bf16(al, bh, acc[nf], 0, 0, 0);
        }
    }

    const int ch0 = wave * 16 + lq * 4;
#pragma unroll
    for (int nf = 0; nf < 4; ++nf) {
        const int n   = nf * 16 + l15;
        const int byo = (ch0 * 2) ^ ((n & 7) << 4);
        bf16x4 hv;
#pragma unroll
        for (int r = 0; r < 4; ++r)
            hv[r] = (short)f2bf(gatef(acc[nf][r]));
        *(bf16x4*)(lds + 2 * XPLANE + n * 256 + byo) = hv;
    }
    __syncthreads();

    f32x4 accr[4], accs[4];
#pragma unroll
    for (int nf = 0; nf < 4; ++nf) {
        accr[nf] = (f32x4){0.f, 0.f, 0.f, 0.f};
        accs[nf] = (f32x4){0.f, 0.f, 0.f, 0.f};
    }
#pragma unroll
    for (int ks = 0; ks < 4; ++ks) {
        const size_t wi = ((size_t)(ks * 8 + wave) * 64 + lane) * 8;
        bf16x8 rh = *(const bf16x8*)(Wrh_i + wi);
        bf16x8 rl = *(const bf16x8*)(Wrl_i + wi);
        bf16x8 sh = *(const bf16x8*)(Wsh_i + wi);
        bf16x8 sl = *(const bf16x8*)(Wsl_i + wi);
#pragma unroll
        for (int nf = 0; nf < 4; ++nf) {
            const int col = nf * 16 + l15;
            const int byo = (ks * 64 + lq * 16) ^ ((col & 7) << 4);
            bf16x8 g = *(const bf16x8*)(lds + 2 * XPLANE + col * 256 + byo);
            accr[nf] = __builtin_amdgcn_mfma_f32_16x16x32_bf16(rh, g, accr[nf], 0, 0, 0);
            accr[nf] = __builtin_amdgcn_mfma_f32_16x16x32_bf16(rl, g, accr[nf], 0, 0, 0);
            accs[nf] = __builtin_amdgcn_mfma_f32_16x16x32_bf16(sh, g, accs[nf], 0, 0, 0);
            accs[nf] = __builtin_amdgcn_mfma_f32_16x16x32_bf16(sl, g, accs[nf], 0, 0, 0);
        }
    }

    const int nt = TFULL - tile0 < 64 ? TFULL - tile0 : 64;
    const float4 brv = *(const float4*)(br + ch0);
    const float4 bsv = *(const float4*)(bs + ch0);
#pragma unroll
    for (int nf = 0; nf < 4; ++nf) {
        const int n = nf * 16 + l15;
        if (n < nt) {
            const int c = tile0 + n;
            const int byo = (ch0 * 2) ^ ((n & 7) << 4);
            bf16x4 ih = *(const bf16x4*)(lds + XPLANE + n * 256 + byo);
            const size_t off = xbase + (size_t)c * RC + ch0;
            bf16x4 il = *(const bf16x4*)(curl + off);
            bf16x4 oh, ol;
            float sk[4];
#pragma unroll
            for (int r = 0; r < 4; ++r) {
                float inv = bf2f((unsigned short)ih[r]) + bf2f((unsigned short)il[r]);
                float rv = accr[nf][r] + ((const float*)&brv)[r] + inv;
                unsigned short h = f2bf(rv);
                oh[r] = (short)h;
                ol[r] = (short)f2bf(rv - bf2f(h));
                sk[r] = accs[nf][r] + ((const float*)&bsv)[r];
            }
            *(bf16x4*)(nxth + off) = oh;
            *(bf16x4*)(nxtl + off) = ol;
            if (c >= TFULL - SKIP_SZ) {
                float* sp = skip + ((size_t)b * RC + ch0) * SKIP_SZ + (c - (TFULL - SKIP_SZ));
#pragma unroll
                for (int r = 0; r < 4; ++r) sp[(size_t)r * SKIP_SZ] = sk[r];
            }
        }
    }
}

// ---------------------------------------------------------------------------
// Fused pair (blk, blk+1) with halo H >= d2 (H in {16,32}). WG core =
// [t0, t0+64); block blk computed over [t0-H, t0+64) (NF1 = (64+H)/16
// frags), y_i kept in LDS (hi for conv, hi+lo for exact residual of
// block blk+1). Numerics bit-identical to two wn_step launches.
// ---------------------------------------------------------------------------
__global__ __launch_bounds__(512, 4) void wn_pair(
    const unsigned short* __restrict__ curh, const unsigned short* __restrict__ curl,
    unsigned short* __restrict__ nxth, unsigned short* __restrict__ nxtl,
    const unsigned short* __restrict__ Wdh, const unsigned short* __restrict__ Wdl,
    const unsigned short* __restrict__ Wrh, const unsigned short* __restrict__ Wrl,
    const unsigned short* __restrict__ Wsh, const unsigned short* __restrict__ Wsl,
    const float* __restrict__ br_all, const float* __restrict__ bs_all,
    float* __restrict__ out, int blk, int d1, int d2, int H, int col0)
{
    __shared__ char lds[LDSB];

    const int tid  = threadIdx.x;
    const int lane = tid & 63;
    const int wave = tid >> 6;
    const int l15  = lane & 15, lq = lane >> 4;
    const int u    = blockIdx.x;
    const int b    = u & 3;
    const int t0   = col0 + (u >> 2) * 64;
    const size_t xbase = (size_t)b * TFULL * RC;
    const int NF1  = (64 + H) >> 4;          // 5 or 6
    const int ch0  = wave * 16 + lq * 4;
    const int nt   = TFULL - t0 < 64 ? TFULL - t0 : 64;

    const unsigned short* Wd1h = Wdh + (size_t)blk * 32768;
    const unsigned short* Wd1l = Wdl + (size_t)blk * 32768;
    const unsigned short* Wd2h = Wd1h + 32768;
    const unsigned short* Wd2l = Wd1l + 32768;
    const unsigned short* Wr1h = Wrh + (size_t)blk * 16384;
    const unsigned short* Wr1l = Wrl + (size_t)blk * 16384;
    const unsigned short* Wr2h = Wr1h + 16384;
    const unsigned short* Wr2l = Wr1l + 16384;
    const unsigned short* Ws1h = Wsh + (size_t)blk * 16384;
    const unsigned short* Ws1l = Wsl + (size_t)blk * 16384;
    const unsigned short* Ws2h = Ws1h + 16384;
    const unsigned short* Ws2l = Ws1l + 16384;
    const float* br1 = br_all + (size_t)blk * RC;
    const float* bs1 = bs_all + (size_t)blk * RC;
    const float* br2 = br1 + RC;
    const float* bs2 = bs1 + RC;
    float* skip1 = out + (size_t)blk * BATCH * RC * SKIP_SZ;
    float* skip2 = skip1 + (size_t)BATCH * RC * SKIP_SZ;

    // ---- stage X hi: plane cols [0,112) = global [t0-48, t0+64)
#pragma unroll
    for (int r = 0; r < 4; ++r) {
        const int j = wave * 4 + r;
        if (j < 28) {
            const int c4   = j * 4;
            const int pcol = c4 + lq;
            const int chs  = l15 ^ (pcol & 7);
            int g = t0 - STGH + pcol;
            g = g < 0 ? 0 : (g > TFULL - 1 ? TFULL - 1 : g);
            const unsigned short* gsrc = curh + xbase + (size_t)g * RC + chs * 8;
            __builtin_amdgcn_global_load_lds(GLB1(gsrc), LDS3(lds + RX + c4 * 256), 16, 0, 0);
        }
    }
    __syncthreads();   // B1

    // ---- block blk dilated conv over NF1 frags (cols t0-H + nf*16 + l15)
    f32x4 a1[6];
#pragma unroll
    for (int nf = 0; nf < 6; ++nf) a1[nf] = (f32x4){0.f, 0.f, 0.f, 0.f};
    const int o0 = STGH - H - d1;
    const int o1 = STGH - H;
#pragma unroll
    for (int ks = 0; ks < 8; ++ks) {
        const int tap = ks >> 2;
        const int kk  = ks & 3;
        const size_t wi = ((size_t)(ks * 8 + wave) * 64 + lane) * 8;
        bf16x8 ah = *(const bf16x8*)(Wd1h + wi);
        bf16x8 al = *(const bf16x8*)(Wd1l + wi);
#pragma unroll
        for (int nf = 0; nf < 6; ++nf) {
            if (nf < NF1) {
                const int pc  = nf * 16 + l15 + (tap ? o1 : o0);
                const int byo = pc * 256 + ((kk * 64 + lq * 16) ^ ((pc & 7) << 4));
                bf16x8 bh = *(const bf16x8*)(lds + RX + byo);
                a1[nf] = __builtin_amdgcn_mfma_f32_16x16x32_bf16(ah, bh, a1[nf], 0, 0, 0);
                a1[nf] = __builtin_amdgcn_mfma_f32_16x16x32_bf16(al, bh, a1[nf], 0, 0, 0);
            }
        }
    }

    // ---- gate_i -> RG
#pragma unroll
    for (int nf = 0; nf < 6; ++nf) {
        if (nf < NF1) {
            const int gc  = nf * 16 + l15;
            const int byo = gc * 256 + ((ch0 * 2) ^ ((gc & 7) << 4));
            bf16x4 hv;
#pragma unroll
            for (int r = 0; r < 4; ++r)
                hv[r] = (short)f2bf(gatef(a1[nf][r]));
            *(bf16x4*)(lds + RG + byo) = hv;
        }
    }
    __syncthreads();   // B2

    // ---- res/skip_i over NF1 frags
    f32x4 r1[6], s1[6];
#pragma unroll
    for (int nf = 0; nf < 6; ++nf) {
        r1[nf] = (f32x4){0.f, 0.f, 0.f, 0.f};
        s1[nf] = (f32x4){0.f, 0.f, 0.f, 0.f};
    }
#pragma unroll
    for (int ks = 0; ks < 4; ++ks) {
        const size_t wi = ((size_t)(ks * 8 + wave) * 64 + lane) * 8;
        bf16x8 rh = *(const bf16x8*)(Wr1h + wi);
        bf16x8 rl = *(const bf16x8*)(Wr1l + wi);
        bf16x8 sh = *(const bf16x8*)(Ws1h + wi);
        bf16x8 sl = *(const bf16x8*)(Ws1l + wi);
#pragma unroll
        for (int nf = 0; nf < 6; ++nf) {
            if (nf < NF1) {
                const int gc  = nf * 16 + l15;
                const int byo = gc * 256 + ((ks * 64 + lq * 16) ^ ((gc & 7) << 4));
                bf16x8 g = *(const bf16x8*)(lds + RG + byo);
                r1[nf] = __builtin_amdgcn_mfma_f32_16x16x32_bf16(rh, g, r1[nf], 0, 0, 0);
                r1[nf] = __builtin_amdgcn_mfma_f32_16x16x32_bf16(rl, g, r1[nf], 0, 0, 0);
                s1[nf] = __builtin_amdgcn_mfma_f32_16x16x32_bf16(sh, g, s1[nf], 0, 0, 0);
                s1[nf] = __builtin_amdgcn_mfma_f32_16x16x32_bf16(sl, g, s1[nf], 0, 0, 0);
            }
        }
    }
    __syncthreads();   // B3 (RG reads done; y_lo will overwrite it)

    // ---- epilogue_i: y_i = r1 + br1 + x_exact; y_hi -> RY (all cols),
    // y_lo -> RG (core cols); skip1 store (core cols).
    {
        const float4 br1v = *(const float4*)(br1 + ch0);
        const float4 bs1v = *(const float4*)(bs1 + ch0);
#pragma unroll
        for (int nf = 0; nf < 6; ++nf) {
            if (nf < NF1) {
                const int yc = nf * 16 + l15;
                const int c  = t0 - H + yc;
                const int pcx = yc + o1;
                bf16x4 xh = *(const bf16x4*)(lds + RX + pcx * 256 + ((ch0 * 2) ^ ((pcx & 7) << 4)));
                int cg = c < 0 ? 0 : (c > TFULL - 1 ? TFULL - 1 : c);
                bf16x4 xl = *(const bf16x4*)(curl + xbase + (size_t)cg * RC + ch0);
                bf16x4 yh4, yl4;
                float sk[4];
#pragma unroll
                for (int r = 0; r < 4; ++r) {
                    float xe = bf2f((unsigned short)xh[r]) + bf2f((unsigned short)xl[r]);
                    float y  = r1[nf][r] + ((const float*)&br1v)[r] + xe;
                    unsigned short h = f2bf(y);
                    yh4[r] = (short)h;
                    yl4[r] = (short)f2bf(y - bf2f(h));
                    sk[r]  = s1[nf][r] + ((const float*)&bs1v)[r];
                }
                *(bf16x4*)(lds + RY + yc * 256 + ((ch0 * 2) ^ ((yc & 7) << 4))) = yh4;
                if (yc >= H) {
                    const int lc = yc - H;
                    *(bf16x4*)(lds + RG + lc * 256 + ((ch0 * 2) ^ ((lc & 7) << 4))) = yl4;
                    if (lc < nt && c >= TFULL - SKIP_SZ) {
                        float* sp = skip1 + ((size_t)b * RC + ch0) * SKIP_SZ + (c - (TFULL - SKIP_SZ));
#pragma unroll
                        for (int r = 0; r < 4; ++r) sp[(size_t)r * SKIP_SZ] = sk[r];
                    }
                }
            }
        }
    }
    __syncthreads();   // B4 (y planes ready; RX dead)

    // ---- block blk+1 dilated over 4 core frags, B from RY
    f32x4 a2[4];
#pragma unroll
    for (int nf = 0; nf < 4; ++nf) a2[nf] = (f32x4){0.f, 0.f, 0.f, 0.f};
    const int p0 = H - d2;
    const int p1 = H;
#pragma unroll
    for (int ks = 0; ks < 8; ++ks) {
        const int tap = ks >> 2;
        const int kk  = ks & 3;
        const size_t wi = ((size_t)(ks * 8 + wave) * 64 + lane) * 8;
        bf16x8 ah = *(const bf16x8*)(Wd2h + wi);
        bf16x8 al = *(const bf16x8*)(Wd2l + wi);
#pragma unroll
        for (int nf = 0; nf < 4; ++nf) {
            const int yi  = nf * 16 + l15 + (tap ? p1 : p0);
            const int byo = yi * 256 + ((kk * 64 + lq * 16) ^ ((yi & 7) << 4));
            bf16x8 bh = *(const bf16x8*)(lds + RY + byo);
            a2[nf] = __builtin_amdgcn_mfma_f32_16x16x32_bf16(ah, bh, a2[nf], 0, 0, 0);
            a2[nf] = __builtin_amdgcn_mfma_f32_16x16x32_bf16(al, bh, a2[nf], 0, 0, 0);
        }
    }

    // ---- gate_{i+1} -> RX (cols 0..63)
#pragma unroll
    for (int nf = 0; nf < 4; ++nf) {
        const int gc  = nf * 16 + l15;
        const int byo = gc * 256 + ((ch0 * 2) ^ ((gc & 7) << 4));
        bf16x4 hv;
#pragma unroll
        for (int r = 0; r < 4; ++r)
            hv[r] = (short)f2bf(gatef(a2[nf][r]));
        *(bf16x4*)(lds + RX + byo) = hv;
    }
    __syncthreads();   // B5

    // ---- res/skip_{i+1}
    f32x4 r2[4], s2[4];
#pragma unroll
    for (int nf = 0; nf < 4; ++nf) {
        r2[nf] = (f32x4){0.f, 0.f, 0.f, 0.f};
        s2[nf] = (f32x4){0.f, 0.f, 0.f, 0.f};
    }
#pragma unroll
    for (int ks = 0; ks < 4; ++ks) {
        const size_t wi = ((size_t)(ks * 8 + wave) * 64 + lane) * 8;
        bf16x8 rh = *(const bf16x8*)(Wr2h + wi);
        bf16x8 rl = *(const bf16x8*)(Wr2l + wi);
        bf16x8 sh = *(const bf16x8*)(Ws2h + wi);
        bf16x8 sl = *(const bf16x8*)(Ws2l + wi);
#pragma unroll
        for (int nf = 0; nf < 4; ++nf) {
            const int gc  = nf * 16 + l15;
            const int byo = gc * 256 + ((ks * 64 + lq * 16) ^ ((gc & 7) << 4));
            bf16x8 g = *(const bf16x8*)(lds + RX + byo);
            r2[nf] = __builtin_amdgcn_mfma_f32_16x16x32_bf16(rh, g, r2[nf], 0, 0, 0);
            r2[nf] = __builtin_amdgcn_mfma_f32_16x16x32_bf16(rl, g, r2[nf], 0, 0, 0);
            s2[nf] = __builtin_amdgcn_mfma_f32_16x16x32_bf16(sh, g, s2[nf], 0, 0, 0);
            s2[nf] = __builtin_amdgcn_mfma_f32_16x16x32_bf16(sl, g, s2[nf], 0, 0, 0);
        }
    }

    // ---- epilogue_{i+1}: y = r2 + br2 + y_i(exact from RY+RG); store stream+skip
    {
        const float4 br2v = *(const float4*)(br2 + ch0);
        const float4 bs2v = *(const float4*)(bs2 + ch0);
#pragma unroll
        for (int nf = 0; nf < 4; ++nf) {
            const int lc = nf * 16 + l15;
            if (lc < nt) {
                const int c  = t0 + lc;
                const int yc = lc + H;
                bf16x4 yh = *(const bf16x4*)(lds + RY + yc * 256 + ((ch0 * 2) ^ ((yc & 7) << 4)));
                bf16x4 yl = *(const bf16x4*)(lds + RG + lc * 256 + ((ch0 * 2) ^ ((lc & 7) << 4)));
                bf16x4 oh, ol;
                float sk[4];
#pragma unroll
                for (int r = 0; r < 4; ++r) {
                    float ye = bf2f((unsigned short)yh[r]) + bf2f((unsigned short)yl[r]);
                    float y  = r2[nf][r] + ((const float*)&br2v)[r] + ye;
                    unsigned short h = f2bf(y);
                    oh[r] = (short)h;
                    ol[r] = (short)f2bf(y - bf2f(h));
                    sk[r] = s2[nf][r] + ((const float*)&bs2v)[r];
                }
                const size_t off = xbase + (size_t)c * RC + ch0;
                *(bf16x4*)(nxth + off) = oh;
                *(bf16x4*)(nxtl + off) = ol;
                if (c >= TFULL - SKIP_SZ) {
                    float* sp = skip2 + ((size_t)b * RC + ch0) * SKIP_SZ + (c - (TFULL - SKIP_SZ));
#pragma unroll
                    for (int r = 0; r < 4; ++r) sp[(size_t)r * SKIP_SZ] = sk[r];
                }
            }
        }
    }
}

extern "C" void kernel_launch(void* const* d_in, const int* in_sizes, int n_in,
                              void* d_out, int out_size, void* d_ws, size_t ws_size,
                              hipStream_t stream) {
    const float* x  = (const float*)d_in[0];
    const float* Wd = (const float*)d_in[1];
    const float* Wr = (const float*)d_in[2];
    const float* br = (const float*)d_in[3];
    const float* Ws = (const float*)d_in[4];
    const float* bs = (const float*)d_in[5];
    float* out = (float*)d_out;

    const size_t SLOT = (size_t)BATCH * TFULL * RC;
    unsigned short* Xs0h = (unsigned short*)d_ws;
    unsigned short* Xs0l = Xs0h + SLOT;
    unsigned short* Xs1h = Xs0l + SLOT;
    unsigned short* Xs1l = Xs1h + SLOT;
    unsigned short* Wdh = Xs1l + SLOT;
    unsigned short* Wdl = Wdh + (size_t)NB * 32768;
    unsigned short* Wrh = Wdl + (size_t)NB * 32768;
    unsigned short* Wrl = Wrh + (size_t)NB * 16384;
    unsigned short* Wsh = Wrl + (size_t)NB * 16384;
    unsigned short* Wsl = Wsh + (size_t)NB * 16384;

    xpose_split<<<dim3(TFULL / 64, RC / 32, BATCH), 256, 0, stream>>>(x, Xs0h, Xs0l);
    {
        int total = NB * 4096 + 2 * NB * 2048;
        wpack<<<dim3((total + 255) / 256), 256, 0, stream>>>(Wd, Wr, Ws, Wdh, Wdl, Wrh, Wrl, Wsh, Wsl);
    }

    static const int pdil[3][3] = {{1, 2, 16}, {4, 8, 16}, {16, 32, 32}};

    int L = TFULL;
    int pp = 0;
    for (int s = 0; s < 4; ++s) {
        // fused pairs: (1,2), (4,8), (16,32)
        for (int p = 0; p < 3; ++p) {
            const int i  = s * 10 + p * 2;
            const int d1 = pdil[p][0], d2 = pdil[p][1], H = pdil[p][2];
            const int Lout = L - d1 - d2;
            const int col0 = TFULL - Lout;
            const int units = ((Lout + 63) >> 6) * BATCH;
            unsigned short* curh = pp ? Xs1h : Xs0h;
            unsigned short* curl = pp ? Xs1l : Xs0l;
            unsigned short* nxth = pp ? Xs0h : Xs1h;
            unsigned short* nxtl = pp ? Xs0l : Xs1l;
            wn_pair<<<dim3(units), dim3(512), 0, stream>>>(
                curh, curl, nxth, nxtl,
                Wdh, Wdl, Wrh, Wrl, Wsh, Wsl,
                br, bs, out, i, d1, d2, H, col0);
            pp ^= 1;
            L = Lout;
        }
        // singles: d = 64, 128, 256, 512
        for (int q = 6; q < 10; ++q) {
            const int i = s * 10 + q;
            const int d = 1 << q;
            const int Lout = L - d;
            const int col0 = TFULL - Lout;
            const int units = ((Lout + 63) >> 6) * BATCH;
            unsigned short* curh = pp ? Xs1h : Xs0h;
            unsigned short* curl = pp ? Xs1l : Xs0l;
            unsigned short* nxth = pp ? Xs0h : Xs1h;
            unsigned short* nxtl = pp ? Xs0l : Xs1l;
            wn_step<<<dim3(units), dim3(512), 0, stream>>>(
                curh, curl, nxth, nxtl,
                Wdh + (size_t)i * 32768, Wdl + (size_t)i * 32768,
                Wrh + (size_t)i * 16384, Wrl + (size_t)i * 16384,
                Wsh + (size_t)i * 16384, Wsl + (size_t)i * 16384,
                br + (size_t)i * RC, bs + (size_t)i * RC,
                out + (size_t)i * BATCH * RC * SKIP_SZ, d, col0);
            pp ^= 1;
            L = Lout;
        }
    }
}

// Round 12
// 664.066 us; speedup vs baseline: 15.4648x; 15.4648x over previous
//
#include <hip/hip_runtime.h>

typedef __attribute__((ext_vector_type(8))) short bf16x8;
typedef __attribute__((ext_vector_type(4))) short bf16x4;
typedef __attribute__((ext_vector_type(4))) float f32x4;

#define TFULL 8192
#define RC 128
#define NB 40
#define BATCH 4
#define SKIP_SZ 4096

#define LDS3(p) ((__attribute__((address_space(3))) void*)(p))
#define GLB1(p) ((const __attribute__((address_space(1))) void*)(p))

// ---- single-block kernel LDS (R10 layout, unchanged) ----
#define XPLANE 16384
#define LDS_BYTES (3 * XPLANE)   // 48 KB

// ---- fused-pair kernel LDS regions (bytes) ----
#define STGH 48                  // staged X left reach (>= H+D1 for all pairs)
#define RX 0                     // 112 cols x 256 B = 28672 : X hi; later gated_{i+1}
#define RG 28672                 // 96 cols  x 256 B = 24576 : gated_i; later y_lo
#define RY (28672 + 24576)       // 96 cols  x 256 B = 24576 : y_i hi
#define LDSB (RY + 24576)        // 77824 B -> 2 WG/CU

__device__ __forceinline__ unsigned short f2bf(float f) {
    unsigned u = __builtin_bit_cast(unsigned, f);
    u += 0x7FFFu + ((u >> 16) & 1u);          // round-to-nearest-even
    return (unsigned short)(u >> 16);
}
__device__ __forceinline__ float bf2f(unsigned short h) {
    unsigned u = ((unsigned)h) << 16;
    return __builtin_bit_cast(float, u);
}
// tanh(y)*sigmoid(y) via one fast exp (clamped; saturation exact).
__device__ __forceinline__ float gatef(float y) {
    float yc = fminf(fmaxf(y, -30.f), 30.f);
    float e  = __expf(-yc);
    float e2 = e * e;
    return (1.f - e2) * __builtin_amdgcn_rcpf(1.f + e2)
                      * __builtin_amdgcn_rcpf(1.f + e);
}

// ---------------------------------------------------------------------------
// Pre-pass 1: transpose x [B][128ch][8192col] fp32 -> hi/lo bf16 [B][col][ch]
// ---------------------------------------------------------------------------
__global__ __launch_bounds__(256) void xpose_split(
    const float* __restrict__ x,
    unsigned short* __restrict__ Xh, unsigned short* __restrict__ Xl)
{
    __shared__ float t[32][65];
    const int col0 = blockIdx.x * 64;
    const int ch0  = blockIdx.y * 32;
    const int b    = blockIdx.z;
    const int tid  = threadIdx.x;
    const int tx = tid & 63, ty = tid >> 6;
#pragma unroll
    for (int i = 0; i < 8; ++i) {
        int ch = ty + i * 4;
        t[ch][tx] = x[((size_t)(b * RC + ch0 + ch)) * TFULL + col0 + tx];
    }
    __syncthreads();
    for (int idx = tid; idx < 64 * 32; idx += 256) {
        int col = idx >> 5, ch = idx & 31;
        float v = t[ch][col];
        unsigned short h = f2bf(v);
        unsigned short l = f2bf(v - bf2f(h));
        size_t off = ((size_t)(b * TFULL + col0 + col)) * RC + ch0 + ch;
        Xh[off] = h;
        Xl[off] = l;
    }
}

// ---------------------------------------------------------------------------
// Pre-pass 2: pack weights into per-MFMA-A-fragment layout, hi/lo bf16.
// A[m][k]: lane l holds rows m=16*mf+(l&15), k = 32*ks + (l>>4)*8 + j.
// Dilated k = tap*128 + i. Dst flat: ((blk*KS*8 + ks*8 + mf)*64 + lane)*8 + j.
// ---------------------------------------------------------------------------
__global__ __launch_bounds__(256) void wpack(
    const float* __restrict__ Wd, const float* __restrict__ Wr, const float* __restrict__ Ws,
    unsigned short* __restrict__ Wdh, unsigned short* __restrict__ Wdl,
    unsigned short* __restrict__ Wrh, unsigned short* __restrict__ Wrl,
    unsigned short* __restrict__ Wsh, unsigned short* __restrict__ Wsl)
{
    const int Nd = NB * 4096;
    const int Nr = NB * 2048;
    int id = blockIdx.x * 256 + threadIdx.x;
    const float* src;
    unsigned short *dh, *dl;
    int blk, rloc;
    bool dil = false;
    size_t dbase;
    if (id < Nd)               { dil = true; blk = id >> 12; rloc = id & 4095; dh = Wdh; dl = Wdl; src = Wd; dbase = (size_t)id * 8; }
    else if (id < Nd + Nr)     { int t = id - Nd;      blk = t >> 11; rloc = t & 2047; dh = Wrh; dl = Wrl; src = Wr; dbase = (size_t)t * 8; }
    else if (id < Nd + 2 * Nr) { int t = id - Nd - Nr; blk = t >> 11; rloc = t & 2047; dh = Wsh; dl = Wsl; src = Ws; dbase = (size_t)t * 8; }
    else return;
    const int ks = rloc >> 9, mf = (rloc >> 6) & 7, lane = rloc & 63;
    const int m = mf * 16 + (lane & 15);
    const int kb = ks * 32 + ((lane >> 4) << 3);
    bf16x8 hv, lv;
#pragma unroll
    for (int j = 0; j < 8; ++j) {
        int k = kb + j;
        float w;
        if (dil) {
            int tap = k >> 7, i = k & 127;
            w = src[((((size_t)blk * 128 + m) * 128) + i) * 2 + tap];
        } else {
            w = src[(((size_t)blk * 128 + m) * 128) + k];
        }
        unsigned short h = f2bf(w);
        hv[j] = (short)h;
        lv[j] = (short)f2bf(w - bf2f(h));
    }
    *(bf16x8*)(dh + dbase) = hv;
    *(bf16x8*)(dl + dbase) = lv;
}

// ---------------------------------------------------------------------------
// Single-block step (R10, proven): 512 thr, wave = mf slot x 64 cols,
// 2-product weights x bf16 X, gated bf16, stream exact hi/lo.
// ---------------------------------------------------------------------------
__global__ __launch_bounds__(512, 4) void wn_step(
    const unsigned short* __restrict__ curh, const unsigned short* __restrict__ curl,
    unsigned short* __restrict__ nxth, unsigned short* __restrict__ nxtl,
    const unsigned short* __restrict__ Wdh_i, const unsigned short* __restrict__ Wdl_i,
    const unsigned short* __restrict__ Wrh_i, const unsigned short* __restrict__ Wrl_i,
    const unsigned short* __restrict__ Wsh_i, const unsigned short* __restrict__ Wsl_i,
    const float* __restrict__ br, const float* __restrict__ bs,
    float* __restrict__ skip, int d, int col0)
{
    __shared__ char lds[LDS_BYTES];

    const int tid  = threadIdx.x;
    const int lane = tid & 63;
    const int wave = tid >> 6;
    const int l15  = lane & 15, lq = lane >> 4;
    const int u    = blockIdx.x;
    const int b    = u & 3;
    const int tile0 = col0 + (u >> 2) * 64;
    const size_t xbase = (size_t)b * TFULL * RC;

#pragma unroll
    for (int r = 0; r < 4; ++r) {
        const int j   = wave * 4 + r;
        const int tap = j >> 4;
        const int c4  = (j & 15) * 4;
        const int col = c4 + lq;
        const int chs = l15 ^ (col & 7);
        int cg_ = tile0 + col;
        cg_ = cg_ > TFULL - 1 ? TFULL - 1 : cg_;
        if (!tap) cg_ -= d;
        const unsigned short* gsrc = curh + xbase + (size_t)cg_ * RC + chs * 8;
        char* ldst = lds + tap * XPLANE + c4 * 256;
        __builtin_amdgcn_global_load_lds(GLB1(gsrc), LDS3(ldst), 16, 0, 0);
    }
    __syncthreads();

    f32x4 acc[4];
#pragma unroll
    for (int nf = 0; nf < 4; ++nf) acc[nf] = (f32x4){0.f, 0.f, 0.f, 0.f};

#pragma unroll
    for (int ks = 0; ks < 8; ++ks) {
        const int tap = ks >> 2;
        const int kk  = ks & 3;
        const size_t wi = ((size_t)(ks * 8 + wave) * 64 + lane) * 8;
        bf16x8 ah = *(const bf16x8*)(Wdh_i + wi);
        bf16x8 al = *(const bf16x8*)(Wdl_i + wi);
#pragma unroll
        for (int nf = 0; nf < 4; ++nf) {
            const int col = nf * 16 + l15;
            const int byo = (kk * 64 + lq * 16) ^ ((col & 7) << 4);
            bf16x8 bh = *(const bf16x8*)(lds + tap * XPLANE + col * 256 + byo);
            acc[nf] = __builtin_amdgcn_mfma_f32_16x16x32_bf16(ah, bh, acc[nf], 0, 0, 0);
            acc[nf] = __builtin_amdgcn_mfma_f32_16x16x32_bf16(al, bh, acc[nf], 0, 0, 0);
        }
    }

    const int ch0 = wave * 16 + lq * 4;
#pragma unroll
    for (int nf = 0; nf < 4; ++nf) {
        const int n   = nf * 16 + l15;
        const int byo = (ch0 * 2) ^ ((n & 7) << 4);
        bf16x4 hv;
#pragma unroll
        for (int r = 0; r < 4; ++r)
            hv[r] = (short)f2bf(gatef(acc[nf][r]));
        *(bf16x4*)(lds + 2 * XPLANE + n * 256 + byo) = hv;
    }
    __syncthreads();

    f32x4 accr[4], accs[4];
#pragma unroll
    for (int nf = 0; nf < 4; ++nf) {
        accr[nf] = (f32x4){0.f, 0.f, 0.f, 0.f};
        accs[nf] = (f32x4){0.f, 0.f, 0.f, 0.f};
    }
#pragma unroll
    for (int ks = 0; ks < 4; ++ks) {
        const size_t wi = ((size_t)(ks * 8 + wave) * 64 + lane) * 8;
        bf16x8 rh = *(const bf16x8*)(Wrh_i + wi);
        bf16x8 rl = *(const bf16x8*)(Wrl_i + wi);
        bf16x8 sh = *(const bf16x8*)(Wsh_i + wi);
        bf16x8 sl = *(const bf16x8*)(Wsl_i + wi);
#pragma unroll
        for (int nf = 0; nf < 4; ++nf) {
            const int col = nf * 16 + l15;
            const int byo = (ks * 64 + lq * 16) ^ ((col & 7) << 4);
            bf16x8 g = *(const bf16x8*)(lds + 2 * XPLANE + col * 256 + byo);
            accr[nf] = __builtin_amdgcn_mfma_f32_16x16x32_bf16(rh, g, accr[nf], 0, 0, 0);
            accr[nf] = __builtin_amdgcn_mfma_f32_16x16x32_bf16(rl, g, accr[nf], 0, 0, 0);
            accs[nf] = __builtin_amdgcn_mfma_f32_16x16x32_bf16(sh, g, accs[nf], 0, 0, 0);
            accs[nf] = __builtin_amdgcn_mfma_f32_16x16x32_bf16(sl, g, accs[nf], 0, 0, 0);
        }
    }

    const int nt = TFULL - tile0 < 64 ? TFULL - tile0 : 64;
    const float4 brv = *(const float4*)(br + ch0);
    const float4 bsv = *(const float4*)(bs + ch0);
#pragma unroll
    for (int nf = 0; nf < 4; ++nf) {
        const int n = nf * 16 + l15;
        if (n < nt) {
            const int c = tile0 + n;
            const int byo = (ch0 * 2) ^ ((n & 7) << 4);
            bf16x4 ih = *(const bf16x4*)(lds + XPLANE + n * 256 + byo);
            const size_t off = xbase + (size_t)c * RC + ch0;
            bf16x4 il = *(const bf16x4*)(curl + off);
            bf16x4 oh, ol;
            float sk[4];
#pragma unroll
            for (int r = 0; r < 4; ++r) {
                float inv = bf2f((unsigned short)ih[r]) + bf2f((unsigned short)il[r]);
                float rv = accr[nf][r] + ((const float*)&brv)[r] + inv;
                unsigned short h = f2bf(rv);
                oh[r] = (short)h;
                ol[r] = (short)f2bf(rv - bf2f(h));
                sk[r] = accs[nf][r] + ((const float*)&bsv)[r];
            }
            *(bf16x4*)(nxth + off) = oh;
            *(bf16x4*)(nxtl + off) = ol;
            if (c >= TFULL - SKIP_SZ) {
                float* sp = skip + ((size_t)b * RC + ch0) * SKIP_SZ + (c - (TFULL - SKIP_SZ));
#pragma unroll
                for (int r = 0; r < 4; ++r) sp[(size_t)r * SKIP_SZ] = sk[r];
            }
        }
    }
}

// ---------------------------------------------------------------------------
// Fused pair (blk, blk+1), TEMPLATED on <D1,D2,H> so NF1, tap offsets and
// halo/core splits are compile-time (R11's runtime params caused VGPR spill:
// 916 us/dispatch, 3.4 GB scratch writes). Math identical to R11 (verified:
// absmax matched bit-exactly).
// ---------------------------------------------------------------------------
template<int D1, int D2, int H>
__global__ __launch_bounds__(512, 4) void wn_pair(
    const unsigned short* __restrict__ curh, const unsigned short* __restrict__ curl,
    unsigned short* __restrict__ nxth, unsigned short* __restrict__ nxtl,
    const unsigned short* __restrict__ Wdh, const unsigned short* __restrict__ Wdl,
    const unsigned short* __restrict__ Wrh, const unsigned short* __restrict__ Wrl,
    const unsigned short* __restrict__ Wsh, const unsigned short* __restrict__ Wsl,
    const float* __restrict__ br_all, const float* __restrict__ bs_all,
    float* __restrict__ out, int blk, int col0)
{
    __shared__ char lds[LDSB];

    constexpr int NF1 = (64 + H) >> 4;       // 5 (H=16) or 6 (H=32)
    constexpr int NHALO = H >> 4;            // frags entirely in halo
    constexpr int O0 = STGH - H - D1;
    constexpr int O1 = STGH - H;
    constexpr int P0 = H - D2;
    constexpr int P1 = H;

    const int tid  = threadIdx.x;
    const int lane = tid & 63;
    const int wave = tid >> 6;
    const int l15  = lane & 15, lq = lane >> 4;
    const int u    = blockIdx.x;
    const int b    = u & 3;
    const int t0   = col0 + (u >> 2) * 64;
    const size_t xbase = (size_t)b * TFULL * RC;
    const int ch0  = wave * 16 + lq * 4;
    const int nt   = TFULL - t0 < 64 ? TFULL - t0 : 64;

    const unsigned short* Wd1h = Wdh + (size_t)blk * 32768;
    const unsigned short* Wd1l = Wdl + (size_t)blk * 32768;
    const unsigned short* Wd2h = Wd1h + 32768;
    const unsigned short* Wd2l = Wd1l + 32768;
    const unsigned short* Wr1h = Wrh + (size_t)blk * 16384;
    const unsigned short* Wr1l = Wrl + (size_t)blk * 16384;
    const unsigned short* Wr2h = Wr1h + 16384;
    const unsigned short* Wr2l = Wr1l + 16384;
    const unsigned short* Ws1h = Wsh + (size_t)blk * 16384;
    const unsigned short* Ws1l = Wsl + (size_t)blk * 16384;
    const unsigned short* Ws2h = Ws1h + 16384;
    const unsigned short* Ws2l = Ws1l + 16384;
    const float* br1 = br_all + (size_t)blk * RC;
    const float* bs1 = bs_all + (size_t)blk * RC;
    const float* br2 = br1 + RC;
    const float* bs2 = bs1 + RC;
    float* skip1 = out + (size_t)blk * BATCH * RC * SKIP_SZ;
    float* skip2 = skip1 + (size_t)BATCH * RC * SKIP_SZ;

    // ---- stage X hi: plane cols [0,112) = global [t0-48, t0+64)
#pragma unroll
    for (int r = 0; r < 4; ++r) {
        const int j = wave * 4 + r;
        if (j < 28) {
            const int c4   = j * 4;
            const int pcol = c4 + lq;
            const int chs  = l15 ^ (pcol & 7);
            int g = t0 - STGH + pcol;
            g = g < 0 ? 0 : (g > TFULL - 1 ? TFULL - 1 : g);
            const unsigned short* gsrc = curh + xbase + (size_t)g * RC + chs * 8;
            __builtin_amdgcn_global_load_lds(GLB1(gsrc), LDS3(lds + RX + c4 * 256), 16, 0, 0);
        }
    }
    __syncthreads();   // B1

    // ---- block blk dilated conv over NF1 frags (cols t0-H + nf*16 + l15)
    f32x4 a1[NF1];
#pragma unroll
    for (int nf = 0; nf < NF1; ++nf) a1[nf] = (f32x4){0.f, 0.f, 0.f, 0.f};
#pragma unroll
    for (int ks = 0; ks < 8; ++ks) {
        const int tap = ks >> 2;
        const int kk  = ks & 3;
        const size_t wi = ((size_t)(ks * 8 + wave) * 64 + lane) * 8;
        bf16x8 ah = *(const bf16x8*)(Wd1h + wi);
        bf16x8 al = *(const bf16x8*)(Wd1l + wi);
#pragma unroll
        for (int nf = 0; nf < NF1; ++nf) {
            const int pc  = nf * 16 + l15 + (tap ? O1 : O0);
            const int byo = pc * 256 + ((kk * 64 + lq * 16) ^ ((pc & 7) << 4));
            bf16x8 bh = *(const bf16x8*)(lds + RX + byo);
            a1[nf] = __builtin_amdgcn_mfma_f32_16x16x32_bf16(ah, bh, a1[nf], 0, 0, 0);
            a1[nf] = __builtin_amdgcn_mfma_f32_16x16x32_bf16(al, bh, a1[nf], 0, 0, 0);
        }
    }

    // ---- gate_i -> RG
#pragma unroll
    for (int nf = 0; nf < NF1; ++nf) {
        const int gc  = nf * 16 + l15;
        const int byo = gc * 256 + ((ch0 * 2) ^ ((gc & 7) << 4));
        bf16x4 hv;
#pragma unroll
        for (int r = 0; r < 4; ++r)
            hv[r] = (short)f2bf(gatef(a1[nf][r]));
        *(bf16x4*)(lds + RG + byo) = hv;
    }
    __syncthreads();   // B2

    // ---- res/skip_i over NF1 frags
    f32x4 r1[NF1], s1[NF1];
#pragma unroll
    for (int nf = 0; nf < NF1; ++nf) {
        r1[nf] = (f32x4){0.f, 0.f, 0.f, 0.f};
        s1[nf] = (f32x4){0.f, 0.f, 0.f, 0.f};
    }
#pragma unroll
    for (int ks = 0; ks < 4; ++ks) {
        const size_t wi = ((size_t)(ks * 8 + wave) * 64 + lane) * 8;
        bf16x8 rh = *(const bf16x8*)(Wr1h + wi);
        bf16x8 rl = *(const bf16x8*)(Wr1l + wi);
        bf16x8 sh = *(const bf16x8*)(Ws1h + wi);
        bf16x8 sl = *(const bf16x8*)(Ws1l + wi);
#pragma unroll
        for (int nf = 0; nf < NF1; ++nf) {
            const int gc  = nf * 16 + l15;
            const int byo = gc * 256 + ((ks * 64 + lq * 16) ^ ((gc & 7) << 4));
            bf16x8 g = *(const bf16x8*)(lds + RG + byo);
            r1[nf] = __builtin_amdgcn_mfma_f32_16x16x32_bf16(rh, g, r1[nf], 0, 0, 0);
            r1[nf] = __builtin_amdgcn_mfma_f32_16x16x32_bf16(rl, g, r1[nf], 0, 0, 0);
            s1[nf] = __builtin_amdgcn_mfma_f32_16x16x32_bf16(sh, g, s1[nf], 0, 0, 0);
            s1[nf] = __builtin_amdgcn_mfma_f32_16x16x32_bf16(sl, g, s1[nf], 0, 0, 0);
        }
    }
    __syncthreads();   // B3 (RG reads done; y_lo will overwrite it)

    // ---- epilogue_i: y_i = r1 + br1 + x_exact; y_hi -> RY (all cols),
    // y_lo -> RG (core cols); skip1 store (core cols).
    {
        const float4 br1v = *(const float4*)(br1 + ch0);
        const float4 bs1v = *(const float4*)(bs1 + ch0);
#pragma unroll
        for (int nf = 0; nf < NF1; ++nf) {
            const int yc = nf * 16 + l15;
            const int c  = t0 - H + yc;
            const int pcx = yc + O1;
            bf16x4 xh = *(const bf16x4*)(lds + RX + pcx * 256 + ((ch0 * 2) ^ ((pcx & 7) << 4)));
            int cg = c < 0 ? 0 : (c > TFULL - 1 ? TFULL - 1 : c);
            bf16x4 xl = *(const bf16x4*)(curl + xbase + (size_t)cg * RC + ch0);
            bf16x4 yh4, yl4;
            float sk[4];
#pragma unroll
            for (int r = 0; r < 4; ++r) {
                float xe = bf2f((unsigned short)xh[r]) + bf2f((unsigned short)xl[r]);
                float y  = r1[nf][r] + ((const float*)&br1v)[r] + xe;
                unsigned short h = f2bf(y);
                yh4[r] = (short)h;
                yl4[r] = (short)f2bf(y - bf2f(h));
                sk[r]  = s1[nf][r] + ((const float*)&bs1v)[r];
            }
            *(bf16x4*)(lds + RY + yc * 256 + ((ch0 * 2) ^ ((yc & 7) << 4))) = yh4;
            if (nf >= NHALO) {   // compile-time fold: core columns
                const int lc = yc - H;
                *(bf16x4*)(lds + RG + lc * 256 + ((ch0 * 2) ^ ((lc & 7) << 4))) = yl4;
                if (lc < nt && c >= TFULL - SKIP_SZ) {
                    float* sp = skip1 + ((size_t)b * RC + ch0) * SKIP_SZ + (c - (TFULL - SKIP_SZ));
#pragma unroll
                    for (int r = 0; r < 4; ++r) sp[(size_t)r * SKIP_SZ] = sk[r];
                }
            }
        }
    }
    __syncthreads();   // B4 (y planes ready; RX dead)

    // ---- block blk+1 dilated over 4 core frags, B from RY
    f32x4 a2[4];
#pragma unroll
    for (int nf = 0; nf < 4; ++nf) a2[nf] = (f32x4){0.f, 0.f, 0.f, 0.f};
#pragma unroll
    for (int ks = 0; ks < 8; ++ks) {
        const int tap = ks >> 2;
        const int kk  = ks & 3;
        const size_t wi = ((size_t)(ks * 8 + wave) * 64 + lane) * 8;
        bf16x8 ah = *(const bf16x8*)(Wd2h + wi);
        bf16x8 al = *(const bf16x8*)(Wd2l + wi);
#pragma unroll
        for (int nf = 0; nf < 4; ++nf) {
            const int yi  = nf * 16 + l15 + (tap ? P1 : P0);
            const int byo = yi * 256 + ((kk * 64 + lq * 16) ^ ((yi & 7) << 4));
            bf16x8 bh = *(const bf16x8*)(lds + RY + byo);
            a2[nf] = __builtin_amdgcn_mfma_f32_16x16x32_bf16(ah, bh, a2[nf], 0, 0, 0);
            a2[nf] = __builtin_amdgcn_mfma_f32_16x16x32_bf16(al, bh, a2[nf], 0, 0, 0);
        }
    }

    // ---- gate_{i+1} -> RX (cols 0..63)
#pragma unroll
    for (int nf = 0; nf < 4; ++nf) {
        const int gc  = nf * 16 + l15;
        const int byo = gc * 256 + ((ch0 * 2) ^ ((gc & 7) << 4));
        bf16x4 hv;
#pragma unroll
        for (int r = 0; r < 4; ++r)
            hv[r] = (short)f2bf(gatef(a2[nf][r]));
        *(bf16x4*)(lds + RX + byo) = hv;
    }
    __syncthreads();   // B5

    // ---- res/skip_{i+1}
    f32x4 r2[4], s2[4];
#pragma unroll
    for (int nf = 0; nf < 4; ++nf) {
        r2[nf] = (f32x4){0.f, 0.f, 0.f, 0.f};
        s2[nf] = (f32x4){0.f, 0.f, 0.f, 0.f};
    }
#pragma unroll
    for (int ks = 0; ks < 4; ++ks) {
        const size_t wi = ((size_t)(ks * 8 + wave) * 64 + lane) * 8;
        bf16x8 rh = *(const bf16x8*)(Wr2h + wi);
        bf16x8 rl = *(const bf16x8*)(Wr2l + wi);
        bf16x8 sh = *(const bf16x8*)(Ws2h + wi);
        bf16x8 sl = *(const bf16x8*)(Ws2l + wi);
#pragma unroll
        for (int nf = 0; nf < 4; ++nf) {
            const int gc  = nf * 16 + l15;
            const int byo = gc * 256 + ((ks * 64 + lq * 16) ^ ((gc & 7) << 4));
            bf16x8 g = *(const bf16x8*)(lds + RX + byo);
            r2[nf] = __builtin_amdgcn_mfma_f32_16x16x32_bf16(rh, g, r2[nf], 0, 0, 0);
            r2[nf] = __builtin_amdgcn_mfma_f32_16x16x32_bf16(rl, g, r2[nf], 0, 0, 0);
            s2[nf] = __builtin_amdgcn_mfma_f32_16x16x32_bf16(sh, g, s2[nf], 0, 0, 0);
            s2[nf] = __builtin_amdgcn_mfma_f32_16x16x32_bf16(sl, g, s2[nf], 0, 0, 0);
        }
    }

    // ---- epilogue_{i+1}: y = r2 + br2 + y_i(exact from RY+RG); store
    {
        const float4 br2v = *(const float4*)(br2 + ch0);
        const float4 bs2v = *(const float4*)(bs2 + ch0);
#pragma unroll
        for (int nf = 0; nf < 4; ++nf) {
            const int lc = nf * 16 + l15;
            if (lc < nt) {
                const int c  = t0 + lc;
                const int yc = lc + H;
                bf16x4 yh = *(const bf16x4*)(lds + RY + yc * 256 + ((ch0 * 2) ^ ((yc & 7) << 4)));
                bf16x4 yl = *(const bf16x4*)(lds + RG + lc * 256 + ((ch0 * 2) ^ ((lc & 7) << 4)));
                bf16x4 oh, ol;
                float sk[4];
#pragma unroll
                for (int r = 0; r < 4; ++r) {
                    float ye = bf2f((unsigned short)yh[r]) + bf2f((unsigned short)yl[r]);
                    float y  = r2[nf][r] + ((const float*)&br2v)[r] + ye;
                    unsigned short h = f2bf(y);
                    oh[r] = (short)h;
                    ol[r] = (short)f2bf(y - bf2f(h));
                    sk[r] = s2[nf][r] + ((const float*)&bs2v)[r];
                }
                const size_t off = xbase + (size_t)c * RC + ch0;
                *(bf16x4*)(nxth + off) = oh;
                *(bf16x4*)(nxtl + off) = ol;
                if (c >= TFULL - SKIP_SZ) {
                    float* sp = skip2 + ((size_t)b * RC + ch0) * SKIP_SZ + (c - (TFULL - SKIP_SZ));
#pragma unroll
                    for (int r = 0; r < 4; ++r) sp[(size_t)r * SKIP_SZ] = sk[r];
                }
            }
        }
    }
}

extern "C" void kernel_launch(void* const* d_in, const int* in_sizes, int n_in,
                              void* d_out, int out_size, void* d_ws, size_t ws_size,
                              hipStream_t stream) {
    const float* x  = (const float*)d_in[0];
    const float* Wd = (const float*)d_in[1];
    const float* Wr = (const float*)d_in[2];
    const float* br = (const float*)d_in[3];
    const float* Ws = (const float*)d_in[4];
    const float* bs = (const float*)d_in[5];
    float* out = (float*)d_out;

    const size_t SLOT = (size_t)BATCH * TFULL * RC;
    unsigned short* Xs0h = (unsigned short*)d_ws;
    unsigned short* Xs0l = Xs0h + SLOT;
    unsigned short* Xs1h = Xs0l + SLOT;
    unsigned short* Xs1l = Xs1h + SLOT;
    unsigned short* Wdh = Xs1l + SLOT;
    unsigned short* Wdl = Wdh + (size_t)NB * 32768;
    unsigned short* Wrh = Wdl + (size_t)NB * 32768;
    unsigned short* Wrl = Wrh + (size_t)NB * 16384;
    unsigned short* Wsh = Wrl + (size_t)NB * 16384;
    unsigned short* Wsl = Wsh + (size_t)NB * 16384;

    xpose_split<<<dim3(TFULL / 64, RC / 32, BATCH), 256, 0, stream>>>(x, Xs0h, Xs0l);
    {
        int total = NB * 4096 + 2 * NB * 2048;
        wpack<<<dim3((total + 255) / 256), 256, 0, stream>>>(Wd, Wr, Ws, Wdh, Wdl, Wrh, Wrl, Wsh, Wsl);
    }

    int L = TFULL;
    int pp = 0;
    for (int s = 0; s < 4; ++s) {
        // fused pairs: (1,2), (4,8), (16,32) — templated instantiations
        for (int p = 0; p < 3; ++p) {
            const int i  = s * 10 + p * 2;
            const int d1 = (p == 0) ? 1 : (p == 1) ? 4 : 16;
            const int d2 = d1 * 2;
            const int Lout = L - d1 - d2;
            const int col0 = TFULL - Lout;
            const int units = ((Lout + 63) >> 6) * BATCH;
            unsigned short* curh = pp ? Xs1h : Xs0h;
            unsigned short* curl = pp ? Xs1l : Xs0l;
            unsigned short* nxth = pp ? Xs0h : Xs1h;
            unsigned short* nxtl = pp ? Xs0l : Xs1l;
            if (p == 0)
                wn_pair<1, 2, 16><<<dim3(units), dim3(512), 0, stream>>>(
                    curh, curl, nxth, nxtl, Wdh, Wdl, Wrh, Wrl, Wsh, Wsl,
                    br, bs, out, i, col0);
            else if (p == 1)
                wn_pair<4, 8, 16><<<dim3(units), dim3(512), 0, stream>>>(
                    curh, curl, nxth, nxtl, Wdh, Wdl, Wrh, Wrl, Wsh, Wsl,
                    br, bs, out, i, col0);
            else
                wn_pair<16, 32, 32><<<dim3(units), dim3(512), 0, stream>>>(
                    curh, curl, nxth, nxtl, Wdh, Wdl, Wrh, Wrl, Wsh, Wsl,
                    br, bs, out, i, col0);
            pp ^= 1;
            L = Lout;
        }
        // singles: d = 64, 128, 256, 512
        for (int q = 6; q < 10; ++q) {
            const int i = s * 10 + q;
            const int d = 1 << q;
            const int Lout = L - d;
            const int col0 = TFULL - Lout;
            const int units = ((Lout + 63) >> 6) * BATCH;
            unsigned short* curh = pp ? Xs1h : Xs0h;
            unsigned short* curl = pp ? Xs1l : Xs0l;
            unsigned short* nxth = pp ? Xs0h : Xs1h;
            unsigned short* nxtl = pp ? Xs0l : Xs1l;
            wn_step<<<dim3(units), dim3(512), 0, stream>>>(
                curh, curl, nxth, nxtl,
                Wdh + (size_t)i * 32768, Wdl + (size_t)i * 32768,
                Wrh + (size_t)i * 16384, Wrl + (size_t)i * 16384,
                Wsh + (size_t)i * 16384, Wsl + (size_t)i * 16384,
                br + (size_t)i * RC, bs + (size_t)i * RC,
                out + (size_t)i * BATCH * RC * SKIP_SZ, d, col0);
            pp ^= 1;
            L = Lout;
        }
    }
}